// Round 2
// baseline (34584.677 us; speedup 1.0000x reference)
//
#include <hip/hip_runtime.h>

// 2-layer biLSTM, B=128 T=256 IN=64 H=256, + fc to [128,1].
// Persistent flag-synced recurrence kernels, fp32 VALU, weights in VGPRs.

constexpr int B_ = 128, T_ = 256, IN_ = 64, H_ = 256;
constexpr int BLK = 256;     // threads per WG
constexpr int NJ  = 16;      // hidden dims per WG
constexpr int NKS = 16;      // k-split factor across threads
constexpr int BB  = 8;       // batch rows per WG
constexpr int NBB = B_ / BB;   // 16 batch blocks
constexpr int NHB = H_ / NJ;   // 16 hidden blocks

__device__ __forceinline__ float sigmoid_(float x) { return 1.f / (1.f + __expf(-x)); }
__device__ __forceinline__ float tanh_(float x)    { return 1.f - 2.f / (1.f + __expf(2.f * x)); }

// KIN: per-step input width (L0: 64 = x, L1: 512 = [fwd0,bwd0]).
// L0 writes full h history into out0[T][B][512]; L1 ping-pongs h and writes hfinal.
template<int KIN, bool L0>
__global__ __launch_bounds__(BLK, L0 ? 2 : 1)
void lstm_kernel(const float* __restrict__ xin,
                 const float* __restrict__ wih_f, const float* __restrict__ whh_f,
                 const float* __restrict__ bih_f, const float* __restrict__ bhh_f,
                 const float* __restrict__ wih_b, const float* __restrict__ whh_b,
                 const float* __restrict__ bih_b, const float* __restrict__ bhh_b,
                 float* __restrict__ hist,     // L0: out0 [T][B][512]; L1: h ping-pong [2][B][H]
                 float* __restrict__ hfinal,   // [B][512] (L1 only)
                 int* __restrict__ flags,      // [2][NBB] accumulating counters
                 int dir_base, int nsteps)
{
  constexpr int KIH = KIN / NKS;  // L0: 4, L1: 32
  constexpr int KHH = H_ / NKS;   // 16

  const int wg  = blockIdx.x;
  const int d   = dir_base + wg / (NBB * NHB);
  const int rem = wg % (NBB * NHB);
  const int bb  = rem / NHB;
  const int hb  = rem % NHB;
  const int tid = threadIdx.x;
  const int j   = tid / NKS;          // 0..15: hidden dim within block
  const int ks  = tid % NKS;          // 0..15: k-slice
  const int jj  = hb * NJ + j;        // hidden index 0..255
  const int b_own = (ks >> 1) & 7;    // batch row owned after reduce-scatter

  const float* wih = d ? wih_b : wih_f;
  const float* whh = d ? whh_b : whh_f;
  const float* bih = d ? bih_b : bih_f;
  const float* bhh = d ? bhh_b : bhh_f;

  // Persistent weight registers. Thread's k-columns: {c*64 + ks*4 + i}
  // (stride-64 chunking -> LDS reads from 16B-aligned, bank-spread addresses).
  float wr_hh[4][KHH];
  float wr_ih[4][KIH];
  float biasr[4];
  #pragma unroll
  for (int t4 = 0; t4 < 4; ++t4) {
    const int row = t4 * H_ + jj;     // PyTorch gate order i,f,g,o
    #pragma unroll
    for (int c = 0; c < KHH / 4; ++c)
      #pragma unroll
      for (int i = 0; i < 4; ++i)
        wr_hh[t4][c * 4 + i] = whh[row * H_ + c * 64 + ks * 4 + i];
    #pragma unroll
    for (int c = 0; c < KIH / 4; ++c)
      #pragma unroll
      for (int i = 0; i < 4; ++i)
        wr_ih[t4][c * 4 + i] = wih[row * KIN + c * 64 + ks * 4 + i];
    biasr[t4] = bih[row] + bhh[row];
  }

  __shared__ float x_tile[BB][KIN];
  __shared__ float h_tile[BB][H_];
  __shared__ float h_out[BB][NJ];

  // h(-1) = 0
  for (int idx = tid; idx < BB * H_ / 4; idx += BLK)
    ((float4*)&h_tile[0][0])[idx] = make_float4(0.f, 0.f, 0.f, 0.f);

  float c_own = 0.f;
  long  guard = 0;                    // total spin budget (deadlock bail-out)
  int*  flagp = &flags[d * NBB + bb];

  const long xts = L0 ? (long)IN_ : (long)B_ * 512;  // stride per time step
  const long xbs = L0 ? (long)T_ * IN_ : 512;        // stride per batch row

  for (int t = 0; t < nsteps; ++t) {
    const int tt = d ? (T_ - 1 - t) : t;

    // Stage x tile (independent of flags -> overlaps the wait).
    {
      const float* xsrc = xin + (long)tt * xts + (long)(bb * BB) * xbs;
      for (int idx = tid; idx < BB * KIN / 4; idx += BLK) {
        const int b = idx / (KIN / 4), k4 = idx % (KIN / 4);
        ((float4*)&x_tile[b][0])[k4] = ((const float4*)(xsrc + b * xbs))[k4];
      }
    }

    if (t > 0) {
      // Wait until all NHB producers of this (d, bb) finished step t-1.
      const int need = NHB * t;
      while (__hip_atomic_load(flagp, __ATOMIC_ACQUIRE, __HIP_MEMORY_SCOPE_AGENT) < need) {
        __builtin_amdgcn_s_sleep(2);
        if (++guard > (1L << 22)) break;   // bail instead of hanging
      }
      const float* hsrc; long hbs;
      if constexpr (L0) {
        const int ttp = d ? tt + 1 : tt - 1;
        hsrc = hist + ((long)ttp * B_ + bb * BB) * 512 + d * H_; hbs = 512;
      } else {
        hsrc = hist + (long)((t - 1) & 1) * B_ * H_ + (long)(bb * BB) * H_; hbs = H_;
      }
      for (int idx = tid; idx < BB * H_ / 4; idx += BLK) {
        const int b = idx / (H_ / 4), k4 = idx % (H_ / 4);
        ((float4*)&h_tile[b][0])[k4] = ((const float4*)(hsrc + b * hbs))[k4];
      }
    }
    __syncthreads();   // SYNC-A: tiles ready

    // Partial gate pre-activations over this thread's k-slice.
    float acc[BB * 4];
    #pragma unroll
    for (int v = 0; v < BB * 4; ++v) acc[v] = 0.f;
    #pragma unroll
    for (int b = 0; b < BB; ++b) {
      #pragma unroll
      for (int c = 0; c < KHH / 4; ++c) {
        const float4 hv = *(const float4*)&h_tile[b][c * 64 + ks * 4];
        #pragma unroll
        for (int t4 = 0; t4 < 4; ++t4) {
          acc[b * 4 + t4] += hv.x * wr_hh[t4][c * 4 + 0];
          acc[b * 4 + t4] += hv.y * wr_hh[t4][c * 4 + 1];
          acc[b * 4 + t4] += hv.z * wr_hh[t4][c * 4 + 2];
          acc[b * 4 + t4] += hv.w * wr_hh[t4][c * 4 + 3];
        }
      }
      #pragma unroll
      for (int c = 0; c < KIH / 4; ++c) {
        const float4 xv = *(const float4*)&x_tile[b][c * 64 + ks * 4];
        #pragma unroll
        for (int t4 = 0; t4 < 4; ++t4) {
          acc[b * 4 + t4] += xv.x * wr_ih[t4][c * 4 + 0];
          acc[b * 4 + t4] += xv.y * wr_ih[t4][c * 4 + 1];
          acc[b * 4 + t4] += xv.z * wr_ih[t4][c * 4 + 2];
          acc[b * 4 + t4] += xv.w * wr_ih[t4][c * 4 + 3];
        }
      }
    }

    // Reduce-scatter across the 16 ks-lanes: 32 values [8b][4t] -> 4 per lane,
    // then a final xor-1 ALLREDUCE so both lanes of each pair hold full sums.
    float r16[16];
    { const bool hi = (ks & 8) != 0;
      #pragma unroll
      for (int v = 0; v < 16; ++v) {
        const float send = hi ? acc[v] : acc[v + 16];
        const float keep = hi ? acc[v + 16] : acc[v];
        r16[v] = keep + __shfl_xor(send, 8, 64);
      } }
    float r8[8];
    { const bool hi = (ks & 4) != 0;
      #pragma unroll
      for (int v = 0; v < 8; ++v) {
        const float send = hi ? r16[v] : r16[v + 8];
        const float keep = hi ? r16[v + 8] : r16[v];
        r8[v] = keep + __shfl_xor(send, 4, 64);
      } }
    float r4[4];
    { const bool hi = (ks & 2) != 0;
      #pragma unroll
      for (int v = 0; v < 4; ++v) {
        const float send = hi ? r8[v] : r8[v + 4];
        const float keep = hi ? r8[v + 4] : r8[v];
        r4[v] = keep + __shfl_xor(send, 2, 64);
      } }
    #pragma unroll
    for (int v = 0; v < 4; ++v)
      r4[v] += __shfl_xor(r4[v], 1, 64);   // <-- the missing 4th butterfly step

    const float pi = r4[0] + biasr[0];
    const float pf = r4[1] + biasr[1];
    const float pg = r4[2] + biasr[2];
    const float po = r4[3] + biasr[3];
    const float ig = sigmoid_(pi), fg = sigmoid_(pf);
    const float gv = tanh_(pg),    og = sigmoid_(po);
    c_own = fg * c_own + ig * gv;
    const float hv = og * tanh_(c_own);

    if ((ks & 1) == 0) h_out[b_own][j] = hv;
    __syncthreads();   // SYNC-B: h_out ready (also protects tile reuse)

    if constexpr (L0) {
      if (tid < BB * NJ) {
        const int b = tid / NJ, jc = tid % NJ;
        hist[((long)tt * B_ + bb * BB + b) * 512 + d * H_ + hb * NJ + jc] = h_out[b][jc];
      }
    } else {
      if (t < nsteps - 1 && tid < BB * NJ) {
        const int b = tid / NJ, jc = tid % NJ;
        hist[(long)(t & 1) * B_ * H_ + (long)(bb * BB + b) * H_ + hb * NJ + jc] = h_out[b][jc];
      }
      if (t == nsteps - 1 && tid < BB * NJ) {
        const int b = tid / NJ, jc = tid % NJ;
        hfinal[(long)(bb * BB + b) * 512 + d * H_ + hb * NJ + jc] = h_out[b][jc];
      }
    }

    __threadfence();     // push h stores to device-coherent point
    __syncthreads();     // SYNC-C: all stores drained before the release
    if (tid == 0)
      __hip_atomic_fetch_add(flagp, 1, __ATOMIC_RELEASE, __HIP_MEMORY_SCOPE_AGENT);
  }
}

__global__ void fc_kernel(const float* __restrict__ hfinal,
                          const float* __restrict__ fc_w,
                          const float* __restrict__ fc_b,
                          float* __restrict__ out)
{
  const int tid = threadIdx.x;      // 512 threads, b = tid/4, quarter = tid%4
  const int b = tid >> 2, q = tid & 3;
  float s = 0.f;
  const float* hp = hfinal + b * 512 + q * 128;
  const float* wp = fc_w + q * 128;
  #pragma unroll 4
  for (int k = 0; k < 128; ++k) s += hp[k] * wp[k];
  s += __shfl_xor(s, 1, 64);
  s += __shfl_xor(s, 2, 64);
  if (q == 0) out[b] = s + fc_b[0];
}

extern "C" void kernel_launch(void* const* d_in, const int* in_sizes, int n_in,
                              void* d_out, int out_size, void* d_ws, size_t ws_size,
                              hipStream_t stream)
{
  const float* x     = (const float*)d_in[0];
  const float* wih0f = (const float*)d_in[1];
  const float* whh0f = (const float*)d_in[2];
  const float* bih0f = (const float*)d_in[3];
  const float* bhh0f = (const float*)d_in[4];
  const float* wih0b = (const float*)d_in[5];
  const float* whh0b = (const float*)d_in[6];
  const float* bih0b = (const float*)d_in[7];
  const float* bhh0b = (const float*)d_in[8];
  const float* wih1f = (const float*)d_in[9];
  const float* whh1f = (const float*)d_in[10];
  const float* bih1f = (const float*)d_in[11];
  const float* bhh1f = (const float*)d_in[12];
  const float* wih1b = (const float*)d_in[13];
  const float* whh1b = (const float*)d_in[14];
  const float* bih1b = (const float*)d_in[15];
  const float* bhh1b = (const float*)d_in[16];
  const float* fcw   = (const float*)d_in[17];
  const float* fcb   = (const float*)d_in[18];

  float* ws     = (float*)d_ws;
  float* out0   = ws;                                    // [T][B][512]
  float* h1buf  = out0 + (size_t)T_ * B_ * 512;          // [2][B][H]
  float* hfinal = h1buf + 2 * B_ * H_;                   // [B][512]
  int*   flags  = (int*)(hfinal + (size_t)B_ * 512);     // 64 ints
  const size_t need_bytes =
      ((size_t)T_ * B_ * 512 + 2 * B_ * H_ + (size_t)B_ * 512) * sizeof(float) + 64 * sizeof(int);
  if (ws_size < need_bytes) return;

  hipMemsetAsync(flags, 0, 64 * sizeof(int), stream);

  // Layer 0: both directions concurrently (512 WGs, all resident at 2/CU).
  lstm_kernel<IN_, true><<<dim3(2 * NBB * NHB), dim3(BLK), 0, stream>>>(
      x, wih0f, whh0f, bih0f, bhh0f, wih0b, whh0b, bih0b, bhh0b,
      out0, nullptr, flags, 0, T_);

  // Layer 1 backward: ONLY the t=T-1 output is needed -> a single step.
  lstm_kernel<512, false><<<dim3(NBB * NHB), dim3(BLK), 0, stream>>>(
      out0, wih1f, whh1f, bih1f, bhh1f, wih1b, whh1b, bih1b, bhh1b,
      h1buf, hfinal, flags + 32, 1, 1);

  // Layer 1 forward: full recurrence.
  lstm_kernel<512, false><<<dim3(NBB * NHB), dim3(BLK), 0, stream>>>(
      out0, wih1f, whh1f, bih1f, bhh1f, wih1b, whh1b, bih1b, bhh1b,
      h1buf, hfinal, flags + 32, 0, T_);

  fc_kernel<<<dim3(1), dim3(512), 0, stream>>>(hfinal, fcw, fcb, (float*)d_out);
}

// Round 3
// 12607.081 us; speedup vs baseline: 2.7433x; 2.7433x over previous
//
#include <hip/hip_runtime.h>

// 2-layer biLSTM, B=128 T=256 IN=64 H=256, + fc to [128,1].
// Persistent flag-synced recurrence kernels, fp32 VALU, weights in VGPRs.
// Cross-WG h exchange via RELAXED agent-scope atomics (device-coherent at
// MALL) -> no fences, no wbl2/inv storms in the step loop.

constexpr int B_ = 128, T_ = 256, IN_ = 64, H_ = 256;
constexpr int BLK = 256;     // threads per WG
constexpr int NJ  = 16;      // hidden dims per WG
constexpr int NKS = 16;      // k-split factor across threads
constexpr int BB  = 8;       // batch rows per WG
constexpr int NBB = B_ / BB;   // 16 batch blocks
constexpr int NHB = H_ / NJ;   // 16 hidden blocks

__device__ __forceinline__ float sigmoid_(float x) { return 1.f / (1.f + __expf(-x)); }
__device__ __forceinline__ float tanh_(float x)    { return 1.f - 2.f / (1.f + __expf(2.f * x)); }

// KIN: per-step input width (L0: 64 = x, L1: 512 = [fwd0,bwd0]).
// L0 writes full h history into out0[T][B][512]; L1 ping-pongs h and writes hfinal.
template<int KIN, bool L0>
__global__ __launch_bounds__(BLK, L0 ? 2 : 1)
void lstm_kernel(const float* __restrict__ xin,
                 const float* __restrict__ wih_f, const float* __restrict__ whh_f,
                 const float* __restrict__ bih_f, const float* __restrict__ bhh_f,
                 const float* __restrict__ wih_b, const float* __restrict__ whh_b,
                 const float* __restrict__ bih_b, const float* __restrict__ bhh_b,
                 float* __restrict__ hist,     // L0: out0 [T][B][512]; L1: h ping-pong [2][B][H]
                 float* __restrict__ hfinal,   // [B][512] (L1 only)
                 int* __restrict__ flags,      // [2][NBB] accumulating counters
                 int dir_base, int nsteps)
{
  constexpr int KIH = KIN / NKS;  // L0: 4, L1: 32
  constexpr int KHH = H_ / NKS;   // 16

  const int wg  = blockIdx.x;
  const int d   = dir_base + wg / (NBB * NHB);
  const int rem = wg % (NBB * NHB);
  const int bb  = rem / NHB;
  const int hb  = rem % NHB;
  const int tid = threadIdx.x;
  const int j   = tid / NKS;          // 0..15: hidden dim within block
  const int ks  = tid % NKS;          // 0..15: k-slice
  const int jj  = hb * NJ + j;        // hidden index 0..255
  const int b_own = (ks >> 1) & 7;    // batch row owned after reduce-scatter

  const float* wih = d ? wih_b : wih_f;
  const float* whh = d ? whh_b : whh_f;
  const float* bih = d ? bih_b : bih_f;
  const float* bhh = d ? bhh_b : bhh_f;

  // Persistent weight registers. Thread's k-columns: {c*64 + ks*4 + i}.
  float wr_hh[4][KHH];
  float wr_ih[4][KIH];
  float biasr[4];
  #pragma unroll
  for (int t4 = 0; t4 < 4; ++t4) {
    const int row = t4 * H_ + jj;     // PyTorch gate order i,f,g,o
    #pragma unroll
    for (int c = 0; c < KHH / 4; ++c)
      #pragma unroll
      for (int i = 0; i < 4; ++i)
        wr_hh[t4][c * 4 + i] = whh[row * H_ + c * 64 + ks * 4 + i];
    #pragma unroll
    for (int c = 0; c < KIH / 4; ++c)
      #pragma unroll
      for (int i = 0; i < 4; ++i)
        wr_ih[t4][c * 4 + i] = wih[row * KIN + c * 64 + ks * 4 + i];
    biasr[t4] = bih[row] + bhh[row];
  }

  __shared__ float x_tile[BB][KIN];
  __shared__ float h_tile[BB][H_];
  __shared__ float h_out[BB][NJ];

  // h(-1) = 0
  for (int idx = tid; idx < BB * H_ / 4; idx += BLK)
    ((float4*)&h_tile[0][0])[idx] = make_float4(0.f, 0.f, 0.f, 0.f);

  float c_own = 0.f;
  long  guard = 0;                    // total spin budget (deadlock bail-out)
  int*  flagp = &flags[d * NBB + bb];

  const long xts = L0 ? (long)IN_ : (long)B_ * 512;  // stride per time step
  const long xbs = L0 ? (long)T_ * IN_ : 512;        // stride per batch row

  for (int t = 0; t < nsteps; ++t) {
    const int tt = d ? (T_ - 1 - t) : t;

    // Stage x tile (plain cached loads; independent of flags).
    {
      const float* xsrc = xin + (long)tt * xts + (long)(bb * BB) * xbs;
      for (int idx = tid; idx < BB * KIN / 4; idx += BLK) {
        const int b = idx / (KIN / 4), k4 = idx % (KIN / 4);
        ((float4*)&x_tile[b][0])[k4] = ((const float4*)(xsrc + b * xbs))[k4];
      }
    }

    if (t > 0) {
      // Wait until all NHB producers of this (d, bb) finished step t-1.
      // RELAXED spin: no cache-maintenance per poll.
      const int need = NHB * t;
      while (__hip_atomic_load(flagp, __ATOMIC_RELAXED, __HIP_MEMORY_SCOPE_AGENT) < need) {
        __builtin_amdgcn_s_sleep(2);
        if (++guard > (1L << 22)) break;   // bail instead of hanging
      }
      const float* hsrc; long hbs;
      if constexpr (L0) {
        const int ttp = d ? tt + 1 : tt - 1;
        hsrc = hist + ((long)ttp * B_ + bb * BB) * 512 + d * H_; hbs = 512;
      } else {
        hsrc = hist + (long)((t - 1) & 1) * B_ * H_ + (long)(bb * BB) * H_; hbs = H_;
      }
      // Device-coherent element loads (bypass possibly-stale L1/L2).
      for (int idx = tid; idx < BB * H_; idx += BLK) {
        const int b = idx / H_, k = idx % H_;
        h_tile[b][k] = __hip_atomic_load(hsrc + b * hbs + k,
                                         __ATOMIC_RELAXED, __HIP_MEMORY_SCOPE_AGENT);
      }
    }
    __syncthreads();   // SYNC-A: tiles ready

    // Partial gate pre-activations over this thread's k-slice.
    float acc[BB * 4];
    #pragma unroll
    for (int v = 0; v < BB * 4; ++v) acc[v] = 0.f;
    #pragma unroll
    for (int b = 0; b < BB; ++b) {
      #pragma unroll
      for (int c = 0; c < KHH / 4; ++c) {
        const float4 hv = *(const float4*)&h_tile[b][c * 64 + ks * 4];
        #pragma unroll
        for (int t4 = 0; t4 < 4; ++t4) {
          acc[b * 4 + t4] += hv.x * wr_hh[t4][c * 4 + 0];
          acc[b * 4 + t4] += hv.y * wr_hh[t4][c * 4 + 1];
          acc[b * 4 + t4] += hv.z * wr_hh[t4][c * 4 + 2];
          acc[b * 4 + t4] += hv.w * wr_hh[t4][c * 4 + 3];
        }
      }
      #pragma unroll
      for (int c = 0; c < KIH / 4; ++c) {
        const float4 xv = *(const float4*)&x_tile[b][c * 64 + ks * 4];
        #pragma unroll
        for (int t4 = 0; t4 < 4; ++t4) {
          acc[b * 4 + t4] += xv.x * wr_ih[t4][c * 4 + 0];
          acc[b * 4 + t4] += xv.y * wr_ih[t4][c * 4 + 1];
          acc[b * 4 + t4] += xv.z * wr_ih[t4][c * 4 + 2];
          acc[b * 4 + t4] += xv.w * wr_ih[t4][c * 4 + 3];
        }
      }
    }

    // Butterfly reduce over the 16 ks-lanes: xor 8,4,2 reduce-scatter,
    // then xor-1 allreduce so each pair holds the full 4-gate sums.
    float r16[16];
    { const bool hi = (ks & 8) != 0;
      #pragma unroll
      for (int v = 0; v < 16; ++v) {
        const float send = hi ? acc[v] : acc[v + 16];
        const float keep = hi ? acc[v + 16] : acc[v];
        r16[v] = keep + __shfl_xor(send, 8, 64);
      } }
    float r8[8];
    { const bool hi = (ks & 4) != 0;
      #pragma unroll
      for (int v = 0; v < 8; ++v) {
        const float send = hi ? r16[v] : r16[v + 8];
        const float keep = hi ? r16[v + 8] : r16[v];
        r8[v] = keep + __shfl_xor(send, 4, 64);
      } }
    float r4[4];
    { const bool hi = (ks & 2) != 0;
      #pragma unroll
      for (int v = 0; v < 4; ++v) {
        const float send = hi ? r8[v] : r8[v + 4];
        const float keep = hi ? r8[v + 4] : r8[v];
        r4[v] = keep + __shfl_xor(send, 2, 64);
      } }
    #pragma unroll
    for (int v = 0; v < 4; ++v)
      r4[v] += __shfl_xor(r4[v], 1, 64);

    const float pi = r4[0] + biasr[0];
    const float pf = r4[1] + biasr[1];
    const float pg = r4[2] + biasr[2];
    const float po = r4[3] + biasr[3];
    const float ig = sigmoid_(pi), fg = sigmoid_(pf);
    const float gv = tanh_(pg),    og = sigmoid_(po);
    c_own = fg * c_own + ig * gv;
    const float hv = og * tanh_(c_own);

    if ((ks & 1) == 0) h_out[b_own][j] = hv;
    __syncthreads();   // SYNC-B: h_out ready (also protects tile reuse)

    if constexpr (L0) {
      if (tid < BB * NJ) {
        const int b = tid / NJ, jc = tid % NJ;
        __hip_atomic_store(&hist[((long)tt * B_ + bb * BB + b) * 512 + d * H_ + hb * NJ + jc],
                           h_out[b][jc], __ATOMIC_RELAXED, __HIP_MEMORY_SCOPE_AGENT);
      }
    } else {
      if (t < nsteps - 1 && tid < BB * NJ) {
        const int b = tid / NJ, jc = tid % NJ;
        __hip_atomic_store(&hist[(long)(t & 1) * B_ * H_ + (long)(bb * BB + b) * H_ + hb * NJ + jc],
                           h_out[b][jc], __ATOMIC_RELAXED, __HIP_MEMORY_SCOPE_AGENT);
      }
      if (t == nsteps - 1 && tid < BB * NJ) {
        const int b = tid / NJ, jc = tid % NJ;
        hfinal[(long)(bb * BB + b) * 512 + d * H_ + hb * NJ + jc] = h_out[b][jc];
      }
    }

    __syncthreads();   // SYNC-C: drains vmcnt(0) -> h stores complete at MALL
    if (tid == 0)
      __hip_atomic_fetch_add(flagp, 1, __ATOMIC_RELAXED, __HIP_MEMORY_SCOPE_AGENT);
  }
}

__global__ void fc_kernel(const float* __restrict__ hfinal,
                          const float* __restrict__ fc_w,
                          const float* __restrict__ fc_b,
                          float* __restrict__ out)
{
  const int tid = threadIdx.x;      // 512 threads, b = tid/4, quarter = tid%4
  const int b = tid >> 2, q = tid & 3;
  float s = 0.f;
  const float* hp = hfinal + b * 512 + q * 128;
  const float* wp = fc_w + q * 128;
  #pragma unroll 4
  for (int k = 0; k < 128; ++k) s += hp[k] * wp[k];
  s += __shfl_xor(s, 1, 64);
  s += __shfl_xor(s, 2, 64);
  if (q == 0) out[b] = s + fc_b[0];
}

extern "C" void kernel_launch(void* const* d_in, const int* in_sizes, int n_in,
                              void* d_out, int out_size, void* d_ws, size_t ws_size,
                              hipStream_t stream)
{
  const float* x     = (const float*)d_in[0];
  const float* wih0f = (const float*)d_in[1];
  const float* whh0f = (const float*)d_in[2];
  const float* bih0f = (const float*)d_in[3];
  const float* bhh0f = (const float*)d_in[4];
  const float* wih0b = (const float*)d_in[5];
  const float* whh0b = (const float*)d_in[6];
  const float* bih0b = (const float*)d_in[7];
  const float* bhh0b = (const float*)d_in[8];
  const float* wih1f = (const float*)d_in[9];
  const float* whh1f = (const float*)d_in[10];
  const float* bih1f = (const float*)d_in[11];
  const float* bhh1f = (const float*)d_in[12];
  const float* wih1b = (const float*)d_in[13];
  const float* whh1b = (const float*)d_in[14];
  const float* bih1b = (const float*)d_in[15];
  const float* bhh1b = (const float*)d_in[16];
  const float* fcw   = (const float*)d_in[17];
  const float* fcb   = (const float*)d_in[18];

  float* ws     = (float*)d_ws;
  float* out0   = ws;                                    // [T][B][512]
  float* h1buf  = out0 + (size_t)T_ * B_ * 512;          // [2][B][H]
  float* hfinal = h1buf + 2 * B_ * H_;                   // [B][512]
  int*   flags  = (int*)(hfinal + (size_t)B_ * 512);     // 64 ints
  const size_t need_bytes =
      ((size_t)T_ * B_ * 512 + 2 * B_ * H_ + (size_t)B_ * 512) * sizeof(float) + 64 * sizeof(int);
  if (ws_size < need_bytes) return;

  hipMemsetAsync(flags, 0, 64 * sizeof(int), stream);

  // Layer 0: both directions concurrently (512 WGs, all resident at 2/CU).
  lstm_kernel<IN_, true><<<dim3(2 * NBB * NHB), dim3(BLK), 0, stream>>>(
      x, wih0f, whh0f, bih0f, bhh0f, wih0b, whh0b, bih0b, bhh0b,
      out0, nullptr, flags, 0, T_);

  // Layer 1 backward: ONLY the t=T-1 output is needed -> a single step.
  lstm_kernel<512, false><<<dim3(NBB * NHB), dim3(BLK), 0, stream>>>(
      out0, wih1f, whh1f, bih1f, bhh1f, wih1b, whh1b, bih1b, bhh1b,
      h1buf, hfinal, flags + 32, 1, 1);

  // Layer 1 forward: full recurrence.
  lstm_kernel<512, false><<<dim3(NBB * NHB), dim3(BLK), 0, stream>>>(
      out0, wih1f, whh1f, bih1f, bhh1f, wih1b, whh1b, bih1b, bhh1b,
      h1buf, hfinal, flags + 32, 0, T_);

  fc_kernel<<<dim3(1), dim3(512), 0, stream>>>(hfinal, fcw, fcb, (float*)d_out);
}

// Round 4
// 4730.119 us; speedup vs baseline: 7.3116x; 2.6653x over previous
//
#include <hip/hip_runtime.h>

// 2-layer biLSTM, B=128 T=256 IN=64 H=256, + fc to [128,1].
// Persistent flag-synced recurrence kernels, fp32 VALU, weights in VGPRs.
// Cross-WG h exchange via RELAXED agent-scope atomics (device-coherent at
// MALL); flags padded to 256B lines and polled by a single lane per WG.

constexpr int B_ = 128, T_ = 256, IN_ = 64, H_ = 256;
constexpr int BLK = 256;     // threads per WG
constexpr int NJ  = 16;      // hidden dims per WG
constexpr int NKS = 16;      // k-split factor across threads
constexpr int BB  = 8;       // batch rows per WG
constexpr int NBB = B_ / BB;   // 16 batch blocks
constexpr int NHB = H_ / NJ;   // 16 hidden blocks
constexpr int FPAD = 64;       // ints per flag slot (256B: one line per flag)

__device__ __forceinline__ float sigmoid_(float x) { return 1.f / (1.f + __expf(-x)); }
__device__ __forceinline__ float tanh_(float x)    { return 1.f - 2.f / (1.f + __expf(2.f * x)); }

// KIN: per-step input width (L0: 64 = x, L1: 512 = [fwd0,bwd0]).
// L0 writes full h history into out0[T][B][512]; L1 ping-pongs h and writes hfinal.
template<int KIN, bool L0>
__global__ __launch_bounds__(BLK, L0 ? 2 : 1)
void lstm_kernel(const float* __restrict__ xin,
                 const float* __restrict__ wih_f, const float* __restrict__ whh_f,
                 const float* __restrict__ bih_f, const float* __restrict__ bhh_f,
                 const float* __restrict__ wih_b, const float* __restrict__ whh_b,
                 const float* __restrict__ bih_b, const float* __restrict__ bhh_b,
                 float* __restrict__ hist,     // L0: out0 [T][B][512]; L1: h ping-pong [2][B][H]
                 float* __restrict__ hfinal,   // [B][512] (L1 only)
                 int* __restrict__ flags,      // [2][NBB] accumulating counters, FPAD-strided
                 int dir_base, int nsteps)
{
  constexpr int KIH = KIN / NKS;  // L0: 4, L1: 32
  constexpr int KHH = H_ / NKS;   // 16

  const int wg  = blockIdx.x;
  const int d   = dir_base + wg / (NBB * NHB);
  const int rem = wg % (NBB * NHB);
  const int bb  = rem / NHB;
  const int hb  = rem % NHB;
  const int tid = threadIdx.x;
  const int j   = tid / NKS;          // 0..15: hidden dim within block
  const int ks  = tid % NKS;          // 0..15: k-slice
  const int jj  = hb * NJ + j;        // hidden index 0..255
  const int b_own = (ks >> 1) & 7;    // batch row owned after reduce-scatter

  const float* wih = d ? wih_b : wih_f;
  const float* whh = d ? whh_b : whh_f;
  const float* bih = d ? bih_b : bih_f;
  const float* bhh = d ? bhh_b : bhh_f;

  // Persistent weight registers. Thread's k-columns: {c*64 + ks*4 + i}.
  float wr_hh[4][KHH];
  float wr_ih[4][KIH];
  float biasr[4];
  #pragma unroll
  for (int t4 = 0; t4 < 4; ++t4) {
    const int row = t4 * H_ + jj;     // PyTorch gate order i,f,g,o
    #pragma unroll
    for (int c = 0; c < KHH / 4; ++c)
      #pragma unroll
      for (int i = 0; i < 4; ++i)
        wr_hh[t4][c * 4 + i] = whh[row * H_ + c * 64 + ks * 4 + i];
    #pragma unroll
    for (int c = 0; c < KIH / 4; ++c)
      #pragma unroll
      for (int i = 0; i < 4; ++i)
        wr_ih[t4][c * 4 + i] = wih[row * KIN + c * 64 + ks * 4 + i];
    biasr[t4] = bih[row] + bhh[row];
  }

  __shared__ float x_tile[BB][KIN];
  __shared__ float h_tile[BB][H_];
  __shared__ float h_out[BB][NJ];

  // h(-1) = 0
  for (int idx = tid; idx < BB * H_ / 4; idx += BLK)
    ((float4*)&h_tile[0][0])[idx] = make_float4(0.f, 0.f, 0.f, 0.f);

  float c_own = 0.f;
  int*  flagp = &flags[(d * NBB + bb) * FPAD];

  const long xts = L0 ? (long)IN_ : (long)B_ * 512;  // stride per time step
  const long xbs = L0 ? (long)T_ * IN_ : 512;        // stride per batch row

  for (int t = 0; t < nsteps; ++t) {
    const int tt = d ? (T_ - 1 - t) : t;

    // Stage x tile (plain cached loads; independent of flags).
    {
      const float* xsrc = xin + (long)tt * xts + (long)(bb * BB) * xbs;
      for (int idx = tid; idx < BB * KIN / 4; idx += BLK) {
        const int b = idx / (KIN / 4), k4 = idx % (KIN / 4);
        ((float4*)&x_tile[b][0])[k4] = ((const float4*)(xsrc + b * xbs))[k4];
      }
    }

    if (t > 0) {
      // Single-lane poll: 1 request per poll per WG; other waves sleep at
      // the HW barrier with zero memory traffic.
      if (tid == 0) {
        const int need = NHB * t;
        long g = 0;
        while (__hip_atomic_load(flagp, __ATOMIC_RELAXED, __HIP_MEMORY_SCOPE_AGENT) < need) {
          __builtin_amdgcn_s_sleep(2);
          if (++g > (1L << 22)) break;   // bail instead of hanging
        }
      }
      __syncthreads();   // poll result published to all waves

      const float* hsrc; long hbs;
      if constexpr (L0) {
        const int ttp = d ? tt + 1 : tt - 1;
        hsrc = hist + ((long)ttp * B_ + bb * BB) * 512 + d * H_; hbs = 512;
      } else {
        hsrc = hist + (long)((t - 1) & 1) * B_ * H_ + (long)(bb * BB) * H_; hbs = H_;
      }
      // Device-coherent element loads (bypass possibly-stale L1/L2).
      for (int idx = tid; idx < BB * H_; idx += BLK) {
        const int b = idx / H_, k = idx % H_;
        h_tile[b][k] = __hip_atomic_load(hsrc + b * hbs + k,
                                         __ATOMIC_RELAXED, __HIP_MEMORY_SCOPE_AGENT);
      }
    }
    __syncthreads();   // SYNC-A: tiles ready

    // Partial gate pre-activations over this thread's k-slice.
    float acc[BB * 4];
    #pragma unroll
    for (int v = 0; v < BB * 4; ++v) acc[v] = 0.f;
    #pragma unroll
    for (int b = 0; b < BB; ++b) {
      #pragma unroll
      for (int c = 0; c < KHH / 4; ++c) {
        const float4 hv = *(const float4*)&h_tile[b][c * 64 + ks * 4];
        #pragma unroll
        for (int t4 = 0; t4 < 4; ++t4) {
          acc[b * 4 + t4] += hv.x * wr_hh[t4][c * 4 + 0];
          acc[b * 4 + t4] += hv.y * wr_hh[t4][c * 4 + 1];
          acc[b * 4 + t4] += hv.z * wr_hh[t4][c * 4 + 2];
          acc[b * 4 + t4] += hv.w * wr_hh[t4][c * 4 + 3];
        }
      }
      #pragma unroll
      for (int c = 0; c < KIH / 4; ++c) {
        const float4 xv = *(const float4*)&x_tile[b][c * 64 + ks * 4];
        #pragma unroll
        for (int t4 = 0; t4 < 4; ++t4) {
          acc[b * 4 + t4] += xv.x * wr_ih[t4][c * 4 + 0];
          acc[b * 4 + t4] += xv.y * wr_ih[t4][c * 4 + 1];
          acc[b * 4 + t4] += xv.z * wr_ih[t4][c * 4 + 2];
          acc[b * 4 + t4] += xv.w * wr_ih[t4][c * 4 + 3];
        }
      }
    }

    // Butterfly reduce over the 16 ks-lanes: xor 8,4,2 reduce-scatter,
    // then xor-1 allreduce so each pair holds the full 4-gate sums.
    float r16[16];
    { const bool hi = (ks & 8) != 0;
      #pragma unroll
      for (int v = 0; v < 16; ++v) {
        const float send = hi ? acc[v] : acc[v + 16];
        const float keep = hi ? acc[v + 16] : acc[v];
        r16[v] = keep + __shfl_xor(send, 8, 64);
      } }
    float r8[8];
    { const bool hi = (ks & 4) != 0;
      #pragma unroll
      for (int v = 0; v < 8; ++v) {
        const float send = hi ? r16[v] : r16[v + 8];
        const float keep = hi ? r16[v + 8] : r16[v];
        r8[v] = keep + __shfl_xor(send, 4, 64);
      } }
    float r4[4];
    { const bool hi = (ks & 2) != 0;
      #pragma unroll
      for (int v = 0; v < 4; ++v) {
        const float send = hi ? r8[v] : r8[v + 4];
        const float keep = hi ? r8[v + 4] : r8[v];
        r4[v] = keep + __shfl_xor(send, 2, 64);
      } }
    #pragma unroll
    for (int v = 0; v < 4; ++v)
      r4[v] += __shfl_xor(r4[v], 1, 64);

    const float pi = r4[0] + biasr[0];
    const float pf = r4[1] + biasr[1];
    const float pg = r4[2] + biasr[2];
    const float po = r4[3] + biasr[3];
    const float ig = sigmoid_(pi), fg = sigmoid_(pf);
    const float gv = tanh_(pg),    og = sigmoid_(po);
    c_own = fg * c_own + ig * gv;
    const float hv = og * tanh_(c_own);

    if ((ks & 1) == 0) h_out[b_own][j] = hv;
    __syncthreads();   // SYNC-B: h_out ready (also protects tile reuse)

    if constexpr (L0) {
      if (tid < BB * NJ) {
        const int b = tid / NJ, jc = tid % NJ;
        __hip_atomic_store(&hist[((long)tt * B_ + bb * BB + b) * 512 + d * H_ + hb * NJ + jc],
                           h_out[b][jc], __ATOMIC_RELAXED, __HIP_MEMORY_SCOPE_AGENT);
      }
    } else {
      if (t < nsteps - 1 && tid < BB * NJ) {
        const int b = tid / NJ, jc = tid % NJ;
        __hip_atomic_store(&hist[(long)(t & 1) * B_ * H_ + (long)(bb * BB + b) * H_ + hb * NJ + jc],
                           h_out[b][jc], __ATOMIC_RELAXED, __HIP_MEMORY_SCOPE_AGENT);
      }
      if (t == nsteps - 1 && tid < BB * NJ) {
        const int b = tid / NJ, jc = tid % NJ;
        hfinal[(long)(bb * BB + b) * 512 + d * H_ + hb * NJ + jc] = h_out[b][jc];
      }
    }

    __syncthreads();   // SYNC-C: drains vmcnt(0) -> h stores complete at MALL
    if (tid == 0)
      __hip_atomic_fetch_add(flagp, 1, __ATOMIC_RELAXED, __HIP_MEMORY_SCOPE_AGENT);
  }
}

__global__ void fc_kernel(const float* __restrict__ hfinal,
                          const float* __restrict__ fc_w,
                          const float* __restrict__ fc_b,
                          float* __restrict__ out)
{
  const int tid = threadIdx.x;      // 512 threads, b = tid/4, quarter = tid%4
  const int b = tid >> 2, q = tid & 3;
  float s = 0.f;
  const float* hp = hfinal + b * 512 + q * 128;
  const float* wp = fc_w + q * 128;
  #pragma unroll 4
  for (int k = 0; k < 128; ++k) s += hp[k] * wp[k];
  s += __shfl_xor(s, 1, 64);
  s += __shfl_xor(s, 2, 64);
  if (q == 0) out[b] = s + fc_b[0];
}

extern "C" void kernel_launch(void* const* d_in, const int* in_sizes, int n_in,
                              void* d_out, int out_size, void* d_ws, size_t ws_size,
                              hipStream_t stream)
{
  const float* x     = (const float*)d_in[0];
  const float* wih0f = (const float*)d_in[1];
  const float* whh0f = (const float*)d_in[2];
  const float* bih0f = (const float*)d_in[3];
  const float* bhh0f = (const float*)d_in[4];
  const float* wih0b = (const float*)d_in[5];
  const float* whh0b = (const float*)d_in[6];
  const float* bih0b = (const float*)d_in[7];
  const float* bhh0b = (const float*)d_in[8];
  const float* wih1f = (const float*)d_in[9];
  const float* whh1f = (const float*)d_in[10];
  const float* bih1f = (const float*)d_in[11];
  const float* bhh1f = (const float*)d_in[12];
  const float* wih1b = (const float*)d_in[13];
  const float* whh1b = (const float*)d_in[14];
  const float* bih1b = (const float*)d_in[15];
  const float* bhh1b = (const float*)d_in[16];
  const float* fcw   = (const float*)d_in[17];
  const float* fcb   = (const float*)d_in[18];

  float* ws     = (float*)d_ws;
  float* out0   = ws;                                    // [T][B][512]
  float* h1buf  = out0 + (size_t)T_ * B_ * 512;          // [2][B][H]
  float* hfinal = h1buf + 2 * B_ * H_;                   // [B][512]
  int*   flags  = (int*)(hfinal + (size_t)B_ * 512);     // 64 slots x FPAD ints
  const size_t need_bytes =
      ((size_t)T_ * B_ * 512 + 2 * B_ * H_ + (size_t)B_ * 512) * sizeof(float)
      + (size_t)64 * FPAD * sizeof(int);
  if (ws_size < need_bytes) return;

  hipMemsetAsync(flags, 0, (size_t)64 * FPAD * sizeof(int), stream);

  // Layer 0: both directions concurrently (512 WGs, all resident at 2/CU).
  lstm_kernel<IN_, true><<<dim3(2 * NBB * NHB), dim3(BLK), 0, stream>>>(
      x, wih0f, whh0f, bih0f, bhh0f, wih0b, whh0b, bih0b, bhh0b,
      out0, nullptr, flags, 0, T_);

  // Layer 1 backward: ONLY the t=T-1 output is needed -> a single step.
  lstm_kernel<512, false><<<dim3(NBB * NHB), dim3(BLK), 0, stream>>>(
      out0, wih1f, whh1f, bih1f, bhh1f, wih1b, whh1b, bih1b, bhh1b,
      h1buf, hfinal, flags + 32 * FPAD, 1, 1);

  // Layer 1 forward: full recurrence.
  lstm_kernel<512, false><<<dim3(NBB * NHB), dim3(BLK), 0, stream>>>(
      out0, wih1f, whh1f, bih1f, bhh1f, wih1b, whh1b, bih1b, bhh1b,
      h1buf, hfinal, flags + 32 * FPAD, 0, T_);

  fc_kernel<<<dim3(1), dim3(512), 0, stream>>>(hfinal, fcw, fcb, (float*)d_out);
}

// Round 5
// 4145.947 us; speedup vs baseline: 8.3418x; 1.1409x over previous
//
#include <hip/hip_runtime.h>

// 2-layer biLSTM, B=128 T=256 IN=64 H=256, + fc to [128,1].
// Persistent flag-synced recurrence kernels, fp32 VALU.
// - Weights pinned in VGPRs via opaque asm (compiler cannot re-load).
// - x-GEMM contribution computed BEFORE the h poll (off the serial chain).
// - Cross-WG h exchange via RELAXED agent-scope 8B atomics (MALL-coherent).
// - Per-producer flag slots (store, not RMW), 256B padded.

constexpr int B_ = 128, T_ = 256, IN_ = 64, H_ = 256;
constexpr int BLK = 256;     // threads per WG
constexpr int NJ  = 16;      // hidden dims per WG
constexpr int NKS = 16;      // k-split factor across threads
constexpr int BB  = 8;       // batch rows per WG
constexpr int NBB = B_ / BB;   // 16 batch blocks
constexpr int NHB = H_ / NJ;   // 16 hidden blocks (producers per group)
constexpr int FPAD = 64;       // ints per flag slot (256B line)

#define KEEP_REG(x) asm volatile("" : "+v"(x))

__device__ __forceinline__ float sigmoid_(float x) { return 1.f / (1.f + __expf(-x)); }
__device__ __forceinline__ float tanh_(float x)    { return 1.f - 2.f / (1.f + __expf(2.f * x)); }

// KIN: per-step input width (L0: 64 = x, L1: 512 = [fwd0,bwd0]).
// L0 writes full h history into out0[T][B][512]; L1 ping-pongs h and writes hfinal.
template<int KIN, bool L0>
__global__ __launch_bounds__(BLK, L0 ? 2 : 1)
void lstm_kernel(const float* __restrict__ xin,
                 const float* __restrict__ wih_f, const float* __restrict__ whh_f,
                 const float* __restrict__ bih_f, const float* __restrict__ bhh_f,
                 const float* __restrict__ wih_b, const float* __restrict__ whh_b,
                 const float* __restrict__ bih_b, const float* __restrict__ bhh_b,
                 float* __restrict__ hist,     // L0: out0 [T][B][512]; L1: h ping-pong [2][B][H]
                 float* __restrict__ hfinal,   // [B][512] (L1 only)
                 int* __restrict__ flags,      // [group][producer] slots, FPAD-strided
                 int dir_base, int nsteps)
{
  constexpr int KIH = KIN / NKS;  // L0: 4, L1: 32
  constexpr int KHH = H_ / NKS;   // 16

  const int wg  = blockIdx.x;
  const int d   = dir_base + wg / (NBB * NHB);
  const int rem = wg % (NBB * NHB);
  const int bb  = rem / NHB;
  const int hb  = rem % NHB;
  const int tid = threadIdx.x;
  const int j   = tid / NKS;          // 0..15: hidden dim within block
  const int ks  = tid % NKS;          // 0..15: k-slice
  const int jj  = hb * NJ + j;        // hidden index 0..255
  const int b_own = (ks >> 1) & 7;    // batch row owned after reduce-scatter
  const int g   = d * NBB + bb;       // sync group

  const float* wih = d ? wih_b : wih_f;
  const float* whh = d ? whh_b : whh_f;
  const float* bih = d ? bih_b : bih_f;
  const float* bhh = d ? bhh_b : bhh_f;

  // Persistent weight registers, pinned via opaque asm so the compiler
  // cannot legally re-load them from global inside the step loop.
  float wr_hh[4][KHH];
  float wr_ih[4][KIH];
  float biasr[4];
  #pragma unroll
  for (int t4 = 0; t4 < 4; ++t4) {
    const int row = t4 * H_ + jj;     // PyTorch gate order i,f,g,o
    #pragma unroll
    for (int c = 0; c < KHH / 4; ++c)
      #pragma unroll
      for (int i = 0; i < 4; ++i) {
        wr_hh[t4][c * 4 + i] = whh[row * H_ + c * 64 + ks * 4 + i];
        KEEP_REG(wr_hh[t4][c * 4 + i]);
      }
    #pragma unroll
    for (int c = 0; c < KIH / 4; ++c)
      #pragma unroll
      for (int i = 0; i < 4; ++i) {
        wr_ih[t4][c * 4 + i] = wih[row * KIN + c * 64 + ks * 4 + i];
        KEEP_REG(wr_ih[t4][c * 4 + i]);
      }
    biasr[t4] = bih[row] + bhh[row];
  }

  __shared__ alignas(16) float x_tile[BB][KIN];
  __shared__ alignas(16) float h_tile[BB][H_];
  __shared__ alignas(16) float h_out[BB][NJ];

  // h(-1) = 0
  for (int idx = tid; idx < BB * H_ / 4; idx += BLK)
    ((float4*)&h_tile[0][0])[idx] = make_float4(0.f, 0.f, 0.f, 0.f);

  float c_own = 0.f;

  const long xts = L0 ? (long)IN_ : (long)B_ * 512;  // stride per time step
  const long xbs = L0 ? (long)T_ * IN_ : 512;        // stride per batch row

  // Prologue: stage x tile for t=0.
  {
    const int tt0 = d ? (T_ - 1) : 0;
    const float* xsrc = xin + (long)tt0 * xts + (long)(bb * BB) * xbs;
    for (int idx = tid; idx < BB * KIN / 4; idx += BLK) {
      const int b = idx / (KIN / 4), k4 = idx % (KIN / 4);
      ((float4*)&x_tile[b][0])[k4] = ((const float4*)(xsrc + b * xbs))[k4];
    }
  }
  __syncthreads();

  for (int t = 0; t < nsteps; ++t) {
    const int tt = d ? (T_ - 1 - t) : t;

    // ---- x-contribution: independent of h, computed BEFORE the poll ----
    float acc[BB * 4];
    #pragma unroll
    for (int v = 0; v < BB * 4; ++v) acc[v] = 0.f;
    #pragma unroll
    for (int b = 0; b < BB; ++b) {
      #pragma unroll
      for (int c = 0; c < KIH / 4; ++c) {
        const float4 xv = *(const float4*)&x_tile[b][c * 64 + ks * 4];
        #pragma unroll
        for (int t4 = 0; t4 < 4; ++t4) {
          acc[b * 4 + t4] += xv.x * wr_ih[t4][c * 4 + 0];
          acc[b * 4 + t4] += xv.y * wr_ih[t4][c * 4 + 1];
          acc[b * 4 + t4] += xv.z * wr_ih[t4][c * 4 + 2];
          acc[b * 4 + t4] += xv.w * wr_ih[t4][c * 4 + 3];
        }
      }
    }

    // ---- wait for h(t-1), then pull it from the device-coherent point ----
    if (t > 0) {
      if (tid < NHB) {
        int* slot = &flags[(g * NHB + tid) * FPAD];
        long gd = 0;
        while (__hip_atomic_load(slot, __ATOMIC_RELAXED, __HIP_MEMORY_SCOPE_AGENT) < t) {
          __builtin_amdgcn_s_sleep(2);
          if (++gd > (1L << 22)) break;   // bail instead of hanging
        }
      }
      __syncthreads();   // all producers done

      const float* hsrc; long hbs;
      if constexpr (L0) {
        const int ttp = d ? tt + 1 : tt - 1;
        hsrc = hist + ((long)ttp * B_ + bb * BB) * 512 + d * H_; hbs = 512;
      } else {
        hsrc = hist + (long)((t - 1) & 1) * B_ * H_ + (long)(bb * BB) * H_; hbs = H_;
      }
      for (int idx = tid; idx < BB * (H_ / 2); idx += BLK) {
        const int b = idx / (H_ / 2), p = idx % (H_ / 2);
        unsigned long long v = __hip_atomic_load(
            (const unsigned long long*)(hsrc + (long)b * hbs) + p,
            __ATOMIC_RELAXED, __HIP_MEMORY_SCOPE_AGENT);
        *(unsigned long long*)&h_tile[b][p * 2] = v;
      }
    }
    __syncthreads();   // SYNC-A: h_tile ready

    // ---- h-contribution (the only post-poll compute) ----
    #pragma unroll
    for (int b = 0; b < BB; ++b) {
      #pragma unroll
      for (int c = 0; c < KHH / 4; ++c) {
        const float4 hv = *(const float4*)&h_tile[b][c * 64 + ks * 4];
        #pragma unroll
        for (int t4 = 0; t4 < 4; ++t4) {
          acc[b * 4 + t4] += hv.x * wr_hh[t4][c * 4 + 0];
          acc[b * 4 + t4] += hv.y * wr_hh[t4][c * 4 + 1];
          acc[b * 4 + t4] += hv.z * wr_hh[t4][c * 4 + 2];
          acc[b * 4 + t4] += hv.w * wr_hh[t4][c * 4 + 3];
        }
      }
    }

    // Butterfly reduce over the 16 ks-lanes: xor 8,4,2 reduce-scatter,
    // then xor-1 allreduce so each pair holds the full 4-gate sums.
    float r16[16];
    { const bool hi = (ks & 8) != 0;
      #pragma unroll
      for (int v = 0; v < 16; ++v) {
        const float send = hi ? acc[v] : acc[v + 16];
        const float keep = hi ? acc[v + 16] : acc[v];
        r16[v] = keep + __shfl_xor(send, 8, 64);
      } }
    float r8[8];
    { const bool hi = (ks & 4) != 0;
      #pragma unroll
      for (int v = 0; v < 8; ++v) {
        const float send = hi ? r16[v] : r16[v + 8];
        const float keep = hi ? r16[v + 8] : r16[v];
        r8[v] = keep + __shfl_xor(send, 4, 64);
      } }
    float r4[4];
    { const bool hi = (ks & 2) != 0;
      #pragma unroll
      for (int v = 0; v < 4; ++v) {
        const float send = hi ? r8[v] : r8[v + 4];
        const float keep = hi ? r8[v + 4] : r8[v];
        r4[v] = keep + __shfl_xor(send, 2, 64);
      } }
    #pragma unroll
    for (int v = 0; v < 4; ++v)
      r4[v] += __shfl_xor(r4[v], 1, 64);

    const float pi = r4[0] + biasr[0];
    const float pf = r4[1] + biasr[1];
    const float pg = r4[2] + biasr[2];
    const float po = r4[3] + biasr[3];
    const float ig = sigmoid_(pi), fg = sigmoid_(pf);
    const float gv = tanh_(pg),    og = sigmoid_(po);
    c_own = fg * c_own + ig * gv;
    const float hv = og * tanh_(c_own);

    if ((ks & 1) == 0) h_out[b_own][j] = hv;
    __syncthreads();   // SYNC-B: h_out ready; acc/x_tile fully consumed

    // Stage x tile for t+1 (overlaps the h store round-trip).
    if (t + 1 < nsteps) {
      const int ttn = d ? (T_ - 2 - t) : (t + 1);
      const float* xsrc = xin + (long)ttn * xts + (long)(bb * BB) * xbs;
      for (int idx = tid; idx < BB * KIN / 4; idx += BLK) {
        const int b = idx / (KIN / 4), k4 = idx % (KIN / 4);
        ((float4*)&x_tile[b][0])[k4] = ((const float4*)(xsrc + b * xbs))[k4];
      }
    }

    // Publish h via 8B device-coherent stores (64 threads, 1 ull each).
    if (tid < BB * (NJ / 2)) {
      const int b = tid / (NJ / 2), pr = tid % (NJ / 2);
      const unsigned long long v = *(const unsigned long long*)&h_out[b][pr * 2];
      if constexpr (L0) {
        __hip_atomic_store(
            (unsigned long long*)&hist[((long)tt * B_ + bb * BB + b) * 512 + d * H_ + hb * NJ] + pr,
            v, __ATOMIC_RELAXED, __HIP_MEMORY_SCOPE_AGENT);
      } else {
        if (t < nsteps - 1)
          __hip_atomic_store(
              (unsigned long long*)&hist[(long)(t & 1) * B_ * H_ + (long)(bb * BB + b) * H_ + hb * NJ] + pr,
              v, __ATOMIC_RELAXED, __HIP_MEMORY_SCOPE_AGENT);
        else
          *((unsigned long long*)&hfinal[(long)(bb * BB + b) * 512 + d * H_ + hb * NJ] + pr) = v;
      }
    }

    __syncthreads();   // SYNC-C: drains vmcnt -> h stores + x stage complete
    if (tid == 0)
      __hip_atomic_store(&flags[(g * NHB + hb) * FPAD], t + 1,
                         __ATOMIC_RELAXED, __HIP_MEMORY_SCOPE_AGENT);
  }
}

__global__ void fc_kernel(const float* __restrict__ hfinal,
                          const float* __restrict__ fc_w,
                          const float* __restrict__ fc_b,
                          float* __restrict__ out)
{
  const int tid = threadIdx.x;      // 512 threads, b = tid/4, quarter = tid%4
  const int b = tid >> 2, q = tid & 3;
  float s = 0.f;
  const float* hp = hfinal + b * 512 + q * 128;
  const float* wp = fc_w + q * 128;
  #pragma unroll 4
  for (int k = 0; k < 128; ++k) s += hp[k] * wp[k];
  s += __shfl_xor(s, 1, 64);
  s += __shfl_xor(s, 2, 64);
  if (q == 0) out[b] = s + fc_b[0];
}

extern "C" void kernel_launch(void* const* d_in, const int* in_sizes, int n_in,
                              void* d_out, int out_size, void* d_ws, size_t ws_size,
                              hipStream_t stream)
{
  const float* x     = (const float*)d_in[0];
  const float* wih0f = (const float*)d_in[1];
  const float* whh0f = (const float*)d_in[2];
  const float* bih0f = (const float*)d_in[3];
  const float* bhh0f = (const float*)d_in[4];
  const float* wih0b = (const float*)d_in[5];
  const float* whh0b = (const float*)d_in[6];
  const float* bih0b = (const float*)d_in[7];
  const float* bhh0b = (const float*)d_in[8];
  const float* wih1f = (const float*)d_in[9];
  const float* whh1f = (const float*)d_in[10];
  const float* bih1f = (const float*)d_in[11];
  const float* bhh1f = (const float*)d_in[12];
  const float* wih1b = (const float*)d_in[13];
  const float* whh1b = (const float*)d_in[14];
  const float* bih1b = (const float*)d_in[15];
  const float* bhh1b = (const float*)d_in[16];
  const float* fcw   = (const float*)d_in[17];
  const float* fcb   = (const float*)d_in[18];

  constexpr int NFLAG = 2 * 32 * NHB * FPAD;  // two kernel regions

  float* ws     = (float*)d_ws;
  float* out0   = ws;                                    // [T][B][512]
  float* h1buf  = out0 + (size_t)T_ * B_ * 512;          // [2][B][H]
  float* hfinal = h1buf + 2 * B_ * H_;                   // [B][512]
  int*   flags  = (int*)(hfinal + (size_t)B_ * 512);
  const size_t need_bytes =
      ((size_t)T_ * B_ * 512 + 2 * B_ * H_ + (size_t)B_ * 512) * sizeof(float)
      + (size_t)NFLAG * sizeof(int);
  if (ws_size < need_bytes) return;

  hipMemsetAsync(flags, 0, (size_t)NFLAG * sizeof(int), stream);

  // Layer 0: both directions concurrently (512 WGs, all resident at 2/CU).
  lstm_kernel<IN_, true><<<dim3(2 * NBB * NHB), dim3(BLK), 0, stream>>>(
      x, wih0f, whh0f, bih0f, bhh0f, wih0b, whh0b, bih0b, bhh0b,
      out0, nullptr, flags, 0, T_);

  // Layer 1 backward: ONLY the t=T-1 output is needed -> a single step.
  lstm_kernel<512, false><<<dim3(NBB * NHB), dim3(BLK), 0, stream>>>(
      out0, wih1f, whh1f, bih1f, bhh1f, wih1b, whh1b, bih1b, bhh1b,
      h1buf, hfinal, flags + 32 * NHB * FPAD, 1, 1);

  // Layer 1 forward: full recurrence.
  lstm_kernel<512, false><<<dim3(NBB * NHB), dim3(BLK), 0, stream>>>(
      out0, wih1f, whh1f, bih1f, bhh1f, wih1b, whh1b, bih1b, bhh1b,
      h1buf, hfinal, flags + 32 * NHB * FPAD, 0, T_);

  fc_kernel<<<dim3(1), dim3(512), 0, stream>>>(hfinal, fcw, fcb, (float*)d_out);
}

// Round 6
// 3895.398 us; speedup vs baseline: 8.8783x; 1.0643x over previous
//
#include <hip/hip_runtime.h>

// 2-layer biLSTM, B=128 T=256 IN=64 H=256, + fc to [128,1].
// Persistent recurrence kernels, fp32 VALU, weights pinned in VGPRs.
// Cross-WG h exchange: POLL-ON-DATA. Each h element is an 8B (tag,value)
// pair in a 2-deep ring, stored/loaded with RELAXED agent-scope atomics
// (device-coherent at MALL). One MALL round-trip per step, no flags, no
// fences. Rings are memset per call so graph replays re-synchronize.

constexpr int B_ = 128, T_ = 256, IN_ = 64, H_ = 256;
constexpr int BLK = 256;     // threads per WG
constexpr int NJ  = 16;      // hidden dims per WG
constexpr int NKS = 16;      // k-split factor across threads
constexpr int BB  = 8;       // batch rows per WG
constexpr int NBB = B_ / BB;   // 16 batch blocks
constexpr int NHB = H_ / NJ;   // 16 hidden blocks (producers per group)

#define KEEP_REG(x) asm volatile("" : "+v"(x))

__device__ __forceinline__ float sigmoid_(float x) { return 1.f / (1.f + __expf(-x)); }
__device__ __forceinline__ float tanh_(float x)    { return 1.f - 2.f / (1.f + __expf(2.f * x)); }

// KIN: per-step input width (L0: 64 = x, L1: 512 = [fwd0,bwd0]).
// L0 writes plain out0[T][B][512] history; both layers exchange h through
// `ring`: [2][B][RW] (tag,value) pairs, RW = 512 (L0, both dirs) / 256 (L1).
template<int KIN, bool L0>
__global__ __launch_bounds__(BLK, L0 ? 2 : 1)
void lstm_kernel(const float* __restrict__ xin,
                 const float* __restrict__ wih_f, const float* __restrict__ whh_f,
                 const float* __restrict__ bih_f, const float* __restrict__ bhh_f,
                 const float* __restrict__ wih_b, const float* __restrict__ whh_b,
                 const float* __restrict__ bih_b, const float* __restrict__ bhh_b,
                 unsigned long long* __restrict__ ring,  // [2][B_][RW] pairs
                 float* __restrict__ out0,     // L0 out: [T][B][512] plain
                 float* __restrict__ hfinal,   // [B][512] (L1 only)
                 int dir_base, int nsteps)
{
  constexpr int KIH = KIN / NKS;   // L0: 4, L1: 32
  constexpr int KHH = H_ / NKS;    // 16
  constexpr int RW  = L0 ? 512 : 256;  // ring row width (pairs)

  const int wg  = blockIdx.x;
  const int d   = dir_base + wg / (NBB * NHB);
  const int rem = wg % (NBB * NHB);
  const int bb  = rem / NHB;
  const int hb  = rem % NHB;
  const int tid = threadIdx.x;
  const int j   = tid / NKS;          // 0..15: hidden dim within block
  const int ks  = tid % NKS;          // 0..15: k-slice
  const int jj  = hb * NJ + j;        // hidden index 0..255
  const int b_own = (ks >> 1) & 7;    // batch row owned after reduce-scatter
  const int doff = L0 ? d * H_ : 0;   // direction offset within ring row

  const float* wih = d ? wih_b : wih_f;
  const float* whh = d ? whh_b : whh_f;
  const float* bih = d ? bih_b : bih_f;
  const float* bhh = d ? bhh_b : bhh_f;

  // Persistent weight registers, pinned so the compiler cannot re-load them.
  float wr_hh[4][KHH];
  float wr_ih[4][KIH];
  float biasr[4];
  #pragma unroll
  for (int t4 = 0; t4 < 4; ++t4) {
    const int row = t4 * H_ + jj;     // PyTorch gate order i,f,g,o
    #pragma unroll
    for (int c = 0; c < KHH / 4; ++c)
      #pragma unroll
      for (int i = 0; i < 4; ++i) {
        wr_hh[t4][c * 4 + i] = whh[row * H_ + c * 64 + ks * 4 + i];
        KEEP_REG(wr_hh[t4][c * 4 + i]);
      }
    #pragma unroll
    for (int c = 0; c < KIH / 4; ++c)
      #pragma unroll
      for (int i = 0; i < 4; ++i) {
        wr_ih[t4][c * 4 + i] = wih[row * KIN + c * 64 + ks * 4 + i];
        KEEP_REG(wr_ih[t4][c * 4 + i]);
      }
    biasr[t4] = bih[row] + bhh[row];
  }

  __shared__ alignas(16) float x_tile[BB][KIN];
  __shared__ alignas(16) float h_tile[BB][H_];
  __shared__ alignas(16) float h_out[BB][NJ];

  // h(-1) = 0
  for (int idx = tid; idx < BB * H_ / 4; idx += BLK)
    ((float4*)&h_tile[0][0])[idx] = make_float4(0.f, 0.f, 0.f, 0.f);

  float c_own = 0.f;

  const long xts = L0 ? (long)IN_ : (long)B_ * 512;  // x stride per time step
  const long xbs = L0 ? (long)T_ * IN_ : 512;        // x stride per batch row

  // Prologue: stage x tile for t=0.
  {
    const int tt0 = d ? (T_ - 1) : 0;
    const float* xsrc = xin + (long)tt0 * xts + (long)(bb * BB) * xbs;
    for (int idx = tid; idx < BB * KIN / 4; idx += BLK) {
      const int b = idx / (KIN / 4), k4 = idx % (KIN / 4);
      ((float4*)&x_tile[b][0])[k4] = ((const float4*)(xsrc + b * xbs))[k4];
    }
  }
  __syncthreads();

  for (int t = 0; t < nsteps; ++t) {
    const int tt = d ? (T_ - 1 - t) : t;

    // ---- x-contribution: independent of h, computed BEFORE the poll ----
    float acc[BB * 4];
    #pragma unroll
    for (int v = 0; v < BB * 4; ++v) acc[v] = 0.f;
    #pragma unroll
    for (int b = 0; b < BB; ++b) {
      #pragma unroll
      for (int c = 0; c < KIH / 4; ++c) {
        const float4 xv = *(const float4*)&x_tile[b][c * 64 + ks * 4];
        #pragma unroll
        for (int t4 = 0; t4 < 4; ++t4) {
          acc[b * 4 + t4] += xv.x * wr_ih[t4][c * 4 + 0];
          acc[b * 4 + t4] += xv.y * wr_ih[t4][c * 4 + 1];
          acc[b * 4 + t4] += xv.z * wr_ih[t4][c * 4 + 2];
          acc[b * 4 + t4] += xv.w * wr_ih[t4][c * 4 + 3];
        }
      }
    }

    // ---- poll-on-data: read h(t-1) pairs, retry stale, into LDS ----
    if (t > 0) {
      const unsigned want = (unsigned)t;   // producer step t-1 wrote tag t
      const unsigned long long* rs =
          ring + ((long)((t - 1) & 1) * B_ + bb * BB) * RW + doff;
      unsigned long long v[8];
      #pragma unroll
      for (int k = 0; k < 8; ++k) {
        const int fp = k * BLK + tid, b = fp >> 8, dim = fp & 255;
        v[k] = __hip_atomic_load(rs + (long)b * RW + dim,
                                 __ATOMIC_RELAXED, __HIP_MEMORY_SCOPE_AGENT);
      }
      long gd = 0;
      for (;;) {
        bool ok = true;
        #pragma unroll
        for (int k = 0; k < 8; ++k) ok &= ((unsigned)(v[k] >> 32) == want);
        if (ok) break;
        if (++gd > (1L << 20)) break;      // bail instead of hanging
        __builtin_amdgcn_s_sleep(1);
        #pragma unroll
        for (int k = 0; k < 8; ++k)
          if ((unsigned)(v[k] >> 32) != want) {
            const int fp = k * BLK + tid, b = fp >> 8, dim = fp & 255;
            v[k] = __hip_atomic_load(rs + (long)b * RW + dim,
                                     __ATOMIC_RELAXED, __HIP_MEMORY_SCOPE_AGENT);
          }
      }
      #pragma unroll
      for (int k = 0; k < 8; ++k) {
        const int fp = k * BLK + tid, b = fp >> 8, dim = fp & 255;
        h_tile[b][dim] = __uint_as_float((unsigned)v[k]);
      }
    }
    __syncthreads();   // SYNC-A: h_tile ready

    // ---- h-contribution (the only post-poll compute) ----
    #pragma unroll
    for (int b = 0; b < BB; ++b) {
      #pragma unroll
      for (int c = 0; c < KHH / 4; ++c) {
        const float4 hv = *(const float4*)&h_tile[b][c * 64 + ks * 4];
        #pragma unroll
        for (int t4 = 0; t4 < 4; ++t4) {
          acc[b * 4 + t4] += hv.x * wr_hh[t4][c * 4 + 0];
          acc[b * 4 + t4] += hv.y * wr_hh[t4][c * 4 + 1];
          acc[b * 4 + t4] += hv.z * wr_hh[t4][c * 4 + 2];
          acc[b * 4 + t4] += hv.w * wr_hh[t4][c * 4 + 3];
        }
      }
    }

    // Butterfly reduce over the 16 ks-lanes (xor 8,4,2 + xor-1 allreduce).
    float r16[16];
    { const bool hi = (ks & 8) != 0;
      #pragma unroll
      for (int v = 0; v < 16; ++v) {
        const float send = hi ? acc[v] : acc[v + 16];
        const float keep = hi ? acc[v + 16] : acc[v];
        r16[v] = keep + __shfl_xor(send, 8, 64);
      } }
    float r8[8];
    { const bool hi = (ks & 4) != 0;
      #pragma unroll
      for (int v = 0; v < 8; ++v) {
        const float send = hi ? r16[v] : r16[v + 8];
        const float keep = hi ? r16[v + 8] : r16[v];
        r8[v] = keep + __shfl_xor(send, 4, 64);
      } }
    float r4[4];
    { const bool hi = (ks & 2) != 0;
      #pragma unroll
      for (int v = 0; v < 4; ++v) {
        const float send = hi ? r8[v] : r8[v + 4];
        const float keep = hi ? r8[v + 4] : r8[v];
        r4[v] = keep + __shfl_xor(send, 2, 64);
      } }
    #pragma unroll
    for (int v = 0; v < 4; ++v)
      r4[v] += __shfl_xor(r4[v], 1, 64);

    const float pi = r4[0] + biasr[0];
    const float pf = r4[1] + biasr[1];
    const float pg = r4[2] + biasr[2];
    const float po = r4[3] + biasr[3];
    const float ig = sigmoid_(pi), fg = sigmoid_(pf);
    const float gv = tanh_(pg),    og = sigmoid_(po);
    c_own = fg * c_own + ig * gv;
    const float hv = og * tanh_(c_own);

    if ((ks & 1) == 0) h_out[b_own][j] = hv;
    __syncthreads();   // SYNC-B: h_out ready; x_tile/h_tile consumed

    // ---- 1) ring publish FIRST (consumers' critical path) ----
    if (t < nsteps - 1 && tid < BB * NJ) {
      const int b = tid >> 4, jc = tid & 15;
      const unsigned long long pv =
          ((unsigned long long)(unsigned)(t + 1) << 32) | __float_as_uint(h_out[b][jc]);
      __hip_atomic_store(ring + ((long)(t & 1) * B_ + bb * BB + b) * RW + doff + hb * NJ + jc,
                         pv, __ATOMIC_RELAXED, __HIP_MEMORY_SCOPE_AGENT);
    }

    // ---- 2) off-chain stores ----
    if constexpr (L0) {
      if (tid < BB * NJ / 2) {   // 64 threads, 8B plain stores of history
        const int b = tid >> 3, pr = tid & 7;
        *(unsigned long long*)&out0[((long)tt * B_ + bb * BB + b) * 512 + d * H_ + hb * NJ + pr * 2] =
            *(const unsigned long long*)&h_out[b][pr * 2];
      }
    } else {
      if (t == nsteps - 1 && tid < BB * NJ / 2) {
        const int b = tid >> 3, pr = tid & 7;
        *(unsigned long long*)&hfinal[(long)(bb * BB + b) * 512 + d * H_ + hb * NJ + pr * 2] =
            *(const unsigned long long*)&h_out[b][pr * 2];
      }
    }

    // ---- 3) stage x tile for t+1 (off the serial chain) ----
    if (t + 1 < nsteps) {
      const int ttn = d ? (T_ - 2 - t) : (t + 1);
      const float* xsrc = xin + (long)ttn * xts + (long)(bb * BB) * xbs;
      for (int idx = tid; idx < BB * KIN / 4; idx += BLK) {
        const int b = idx / (KIN / 4), k4 = idx % (KIN / 4);
        ((float4*)&x_tile[b][0])[k4] = ((const float4*)(xsrc + b * xbs))[k4];
      }
    }
    __syncthreads();   // SYNC-C: x_tile staged; LDS safe for next iter
  }
}

__global__ void fc_kernel(const float* __restrict__ hfinal,
                          const float* __restrict__ fc_w,
                          const float* __restrict__ fc_b,
                          float* __restrict__ out)
{
  const int tid = threadIdx.x;      // 512 threads, b = tid/4, quarter = tid%4
  const int b = tid >> 2, q = tid & 3;
  float s = 0.f;
  const float* hp = hfinal + b * 512 + q * 128;
  const float* wp = fc_w + q * 128;
  #pragma unroll 4
  for (int k = 0; k < 128; ++k) s += hp[k] * wp[k];
  s += __shfl_xor(s, 1, 64);
  s += __shfl_xor(s, 2, 64);
  if (q == 0) out[b] = s + fc_b[0];
}

extern "C" void kernel_launch(void* const* d_in, const int* in_sizes, int n_in,
                              void* d_out, int out_size, void* d_ws, size_t ws_size,
                              hipStream_t stream)
{
  const float* x     = (const float*)d_in[0];
  const float* wih0f = (const float*)d_in[1];
  const float* whh0f = (const float*)d_in[2];
  const float* bih0f = (const float*)d_in[3];
  const float* bhh0f = (const float*)d_in[4];
  const float* wih0b = (const float*)d_in[5];
  const float* whh0b = (const float*)d_in[6];
  const float* bih0b = (const float*)d_in[7];
  const float* bhh0b = (const float*)d_in[8];
  const float* wih1f = (const float*)d_in[9];
  const float* whh1f = (const float*)d_in[10];
  const float* bih1f = (const float*)d_in[11];
  const float* bhh1f = (const float*)d_in[12];
  const float* wih1b = (const float*)d_in[13];
  const float* whh1b = (const float*)d_in[14];
  const float* bih1b = (const float*)d_in[15];
  const float* bhh1b = (const float*)d_in[16];
  const float* fcw   = (const float*)d_in[17];
  const float* fcb   = (const float*)d_in[18];

  const size_t n_out0  = (size_t)T_ * B_ * 512;   // floats
  const size_t n_hfin  = (size_t)B_ * 512;        // floats
  const size_t n_ring0 = 2ull * B_ * 512;         // ull pairs
  const size_t n_ring1 = 2ull * B_ * 256;         // ull pairs

  float* ws     = (float*)d_ws;
  float* out0   = ws;
  float* hfinal = out0 + n_out0;
  unsigned long long* ring0 = (unsigned long long*)(hfinal + n_hfin);
  unsigned long long* ring1 = ring0 + n_ring0;

  const size_t need_bytes = (n_out0 + n_hfin) * sizeof(float)
                          + (n_ring0 + n_ring1) * sizeof(unsigned long long);
  if (ws_size < need_bytes) return;

  // Reset ring tags so every (graph-replayed) run re-synchronizes honestly.
  hipMemsetAsync(ring0, 0, (n_ring0 + n_ring1) * sizeof(unsigned long long), stream);

  // Layer 0: both directions concurrently (512 WGs, all resident at 2/CU).
  lstm_kernel<IN_, true><<<dim3(2 * NBB * NHB), dim3(BLK), 0, stream>>>(
      x, wih0f, whh0f, bih0f, bhh0f, wih0b, whh0b, bih0b, bhh0b,
      ring0, out0, nullptr, 0, T_);

  // Layer 1 backward: ONLY the t=T-1 output is needed -> a single step.
  lstm_kernel<512, false><<<dim3(NBB * NHB), dim3(BLK), 0, stream>>>(
      out0, wih1f, whh1f, bih1f, bhh1f, wih1b, whh1b, bih1b, bhh1b,
      ring1, nullptr, hfinal, 1, 1);

  // Layer 1 forward: full recurrence.
  lstm_kernel<512, false><<<dim3(NBB * NHB), dim3(BLK), 0, stream>>>(
      out0, wih1f, whh1f, bih1f, bhh1f, wih1b, whh1b, bih1b, bhh1b,
      ring1, nullptr, hfinal, 0, T_);

  fc_kernel<<<dim3(1), dim3(512), 0, stream>>>(hfinal, fcw, fcb, (float*)d_out);
}